// Round 8
// baseline (789.519 us; speedup 1.0000x reference)
//
#include <hip/hip_runtime.h>

namespace {

constexpr int T = 465;        // (N-1)(N-2)/2 triplets per center
constexpr int M = 31;         // "others" count
constexpr float FCUT = 3.5f;
constexpr float PI_OVER_CUT = 0.8975979010256552f; // pi/3.5
constexpr int REC = 12;       // floats per compacted row record
constexpr int K2_BLOCKS = 512;
constexpr int MAXROWS_HARD = 1024 * 480;

__device__ __forceinline__ float ftanh(float x) {
    x = fminf(fmaxf(x, -15.0f), 15.0f);
    const float e = __expf(2.0f * x);
    return (e - 1.0f) * __builtin_amdgcn_rcpf(e + 1.0f);
}

// ---------------- K1: compact active triplets into global row list ----------
// 4 waves per block, one center per wave.
__global__ __launch_bounds__(256, 4)
void feat_kernel(const float* __restrict__ D, const float* __restrict__ Z,
                 float* __restrict__ rows, int* __restrict__ ctr, int maxrows)
{
    const int lane = threadIdx.x & 63;
    const int center = blockIdx.x * 4 + (threadIdx.x >> 6);
    const int bi = center >> 5, i = center & 31;
    const float* __restrict__ Drow = D + bi * 1024;
    const float* __restrict__ Zrow = Z + bi * 32;
    const float z_i = Zrow[i];

    unsigned long long masks[8];
    int cnt = 0;
    #pragma unroll
    for (int rnd = 0; rnd < 8; ++rnd) {
        const int t = rnd * 64 + lane;
        bool act = false;
        if (t < T) {
            int a = 0, rem = t;
            while (rem >= M - 1 - a) { rem -= M - 1 - a; ++a; }
            const int b = a + 1 + rem;
            const int j = a + (a >= i);
            const int k = b + (b >= i);
            const float rij = Drow[i * 32 + j];
            const float rik = Drow[i * 32 + k];
            act = (rij < FCUT) && (rik < FCUT);
        }
        masks[rnd] = __ballot(act);
        cnt += (int)__popcll(masks[rnd]);
    }
    const int padded = (cnt + 15) & ~15;   // every 16-segment belongs to one center
    if (padded == 0) return;
    int base = 0;
    if (lane == 0) base = atomicAdd(ctr, padded);
    base = __shfl(base, 0);
    if (base + padded > maxrows) return;

    int pre = 0;
    #pragma unroll
    for (int rnd = 0; rnd < 8; ++rnd) {
        const unsigned long long mb = masks[rnd];
        const bool act = (mb >> lane) & 1ull;
        const int slot = base + pre + (int)__popcll(mb & ((1ull << lane) - 1ull));
        pre += (int)__popcll(mb);
        if (act) {
            const int t = rnd * 64 + lane;
            int a = 0, rem = t;
            while (rem >= M - 1 - a) { rem -= M - 1 - a; ++a; }
            const int b = a + 1 + rem;
            const int j = a + (a >= i);
            const int k = b + (b >= i);
            const float rij = Drow[i * 32 + j];
            const float rik = Drow[i * 32 + k];
            const float rjk = Drow[j * 32 + k];
            const float zj = Zrow[j], zk = Zrow[k];
            const float rij2 = rij * rij, rik2 = rik * rik, rjk2 = rjk * rjk;
            const float ci = (rij2 + rik2 - rjk2) / fmaxf(2.f * rij * rik, 1e-10f);
            const float cj = (rij2 + rjk2 - rik2) / fmaxf(2.f * rij * rjk, 1e-10f);
            const float ck = (rik2 + rjk2 - rij2) / fmaxf(2.f * rik * rjk, 1e-10f);
            const float g0 = rij + rik + rjk;
            const float g1 = rij * rik + rij * rjk + rik * rjk;
            const float g2 = rij * rik * rjk;
            const float rg = 1.0f / (sqrtf(g0 * g0 + g1 * g1 + g2 * g2) + 1e-7f);
            const float s0 = z_i + zj + zk;
            const float s1 = ci + cj + ck;
            const float s2 = z_i * (zj + zk) + zj * zk - ci * (cj + ck) - cj * ck;
            const float s3 = z_i * (cj + ck) + ci * (zj + zk) + zj * ck + cj * zk;
            const float s4 = z_i * (zj * zk - cj * ck) - ci * (zj * ck + cj * zk);
            const float s5 = z_i * (zj * ck + cj * zk) + ci * (zj * zk - cj * ck);
            const float rs = 1.0f / (sqrtf(s0*s0 + s1*s1 + s2*s2 + s3*s3 + s4*s4 + s5*s5) + 1e-7f);
            const float fij = 0.5f * cosf(PI_OVER_CUT * rij) + 0.5f;
            const float fik = 0.5f * cosf(PI_OVER_CUT * rik) + 0.5f;
            float4* dst = (float4*)(rows + (size_t)slot * REC);
            dst[0] = make_float4(g0 * rg, g1 * rg, g2 * rg, s0 * rs);
            dst[1] = make_float4(s1 * rs, s2 * rs, s3 * rs, s4 * rs);
            dst[2] = make_float4(s5 * rs, fij * fik, __int_as_float(center), 0.f);
        }
    }
    for (int p = cnt + lane; p < padded; p += 64) {
        float4* dst = (float4*)(rows + (size_t)(base + p) * REC);
        dst[0] = make_float4(0.f, 0.f, 0.f, 0.f);
        dst[1] = make_float4(0.f, 0.f, 0.f, 0.f);
        dst[2] = make_float4(0.f, 0.f, __int_as_float(center), 0.f);
    }
}

// acc[0..16) += sum_kk x[kk][lane] * W[kk][wcol..wcol+16).
// Weight loads: global_load_dwordx4, all lanes same address -> one 16B L1
// transaction, broadcast; counted by vmcnt (independent of LDS lgkmcnt) so
// the compiler can pipeline them across the unrolled kk loop. Only the x
// read (ds_read_b32) touches the LDS pipe.
template<int INF, int LDW>
__device__ __forceinline__ void accum_v(const float* __restrict__ Wcol,
                                        const float* __restrict__ xin,
                                        int lane, float acc[16])
{
    const float4* __restrict__ w = (const float4*)Wcol;
    #pragma unroll 4
    for (int kk = 0; kk < INF; ++kk) {
        const float4 w0 = w[kk * (LDW / 4) + 0];
        const float4 w1 = w[kk * (LDW / 4) + 1];
        const float4 w2 = w[kk * (LDW / 4) + 2];
        const float4 w3 = w[kk * (LDW / 4) + 3];
        const float x = xin[kk * 64 + lane];
        acc[ 0] = fmaf(x, w0.x, acc[ 0]);  acc[ 1] = fmaf(x, w0.y, acc[ 1]);
        acc[ 2] = fmaf(x, w0.z, acc[ 2]);  acc[ 3] = fmaf(x, w0.w, acc[ 3]);
        acc[ 4] = fmaf(x, w1.x, acc[ 4]);  acc[ 5] = fmaf(x, w1.y, acc[ 5]);
        acc[ 6] = fmaf(x, w1.z, acc[ 6]);  acc[ 7] = fmaf(x, w1.w, acc[ 7]);
        acc[ 8] = fmaf(x, w2.x, acc[ 8]);  acc[ 9] = fmaf(x, w2.y, acc[ 9]);
        acc[10] = fmaf(x, w2.z, acc[10]);  acc[11] = fmaf(x, w2.w, acc[11]);
        acc[12] = fmaf(x, w3.x, acc[12]);  acc[13] = fmaf(x, w3.y, acc[13]);
        acc[14] = fmaf(x, w3.z, acc[14]);  acc[15] = fmaf(x, w3.w, acc[15]);
    }
}

__device__ __forceinline__ void bias_v(const float* __restrict__ Bcol, float acc[16]) {
    const float4* __restrict__ b = (const float4*)Bcol;
    const float4 b0 = b[0], b1 = b[1], b2 = b[2], b3 = b[3];
    acc[0]=b0.x; acc[1]=b0.y; acc[2]=b0.z; acc[3]=b0.w;
    acc[4]=b1.x; acc[5]=b1.y; acc[6]=b1.z; acc[7]=b1.w;
    acc[8]=b2.x; acc[9]=b2.y; acc[10]=b2.z; acc[11]=b2.w;
    acc[12]=b3.x; acc[13]=b3.y; acc[14]=b3.z; acc[15]=b3.w;
}

// ---------------- K2: MLP over compacted rows -------------------------------
// 256 threads (4 waves) per 64-row tile; waves split the output dim (16 cols
// each, lane = row). Weights via VMEM broadcast loads; activations in shared
// [feat][row] LDS. ~51 KB LDS -> 3 blocks/CU = 12 waves/CU.
__global__ __launch_bounds__(256, 3)
void mlp_kernel(const float* __restrict__ rows, const int* __restrict__ ctr,
                const float* __restrict__ W0, const float* __restrict__ B0,
                const float* __restrict__ W1, const float* __restrict__ B1,
                const float* __restrict__ W2, const float* __restrict__ B2,
                const float* __restrict__ W3, const float* __restrict__ B3,
                const float* __restrict__ W4, const float* __restrict__ B4,
                const float* __restrict__ W5, const float* __restrict__ B5,
                const float* __restrict__ W6, const float* __restrict__ B6,
                float* __restrict__ out, int maxrows)
{
    __shared__ float Ab[64 * 64];
    __shared__ float Bb[64 * 64];
    __shared__ float Cb[64 * 64];
    __shared__ float Fb[9 * 64];
    __shared__ float SMb[64];
    __shared__ int   CTb[64];

    const int t = threadIdx.x;
    const int lane = t & 63;
    const int wcol = (t >> 6) * 16;   // wave-uniform, lives in VGPR -> VMEM loads

    int nrows = *ctr;                 // multiple of 16
    if (nrows > maxrows) nrows = maxrows & ~15;

    for (int tile = blockIdx.x; tile * 64 < nrows; tile += K2_BLOCKS) {
        __syncthreads();   // previous tile fully consumed LDS (incl. SM/CT in L6)
        if (t < 64) {
            const int r = tile * 64 + t;
            float4 v0 = make_float4(0,0,0,0), v1 = v0, v2 = v0;
            if (r < nrows) {
                const float4* rec = (const float4*)(rows + (size_t)r * REC);
                v0 = rec[0]; v1 = rec[1]; v2 = rec[2];
            } else {
                v2.z = __int_as_float(-1);   // phantom row: no atomics
            }
            Fb[0*64+t]=v0.x; Fb[1*64+t]=v0.y; Fb[2*64+t]=v0.z;
            Fb[3*64+t]=v0.w; Fb[4*64+t]=v1.x; Fb[5*64+t]=v1.y;
            Fb[6*64+t]=v1.z; Fb[7*64+t]=v1.w; Fb[8*64+t]=v2.x;
            SMb[t] = v2.y;
            CTb[t] = __float_as_int(v2.z);
        }
        __syncthreads();

        float acc[16];

        // L0: F -> A (x_res)
        bias_v(B0 + wcol, acc);
        accum_v<9, 64>(W0 + wcol, Fb, lane, acc);
        #pragma unroll
        for (int q = 0; q < 16; ++q) Ab[(wcol + q) * 64 + lane] = ftanh(acc[q]);
        __syncthreads();

        // L1: A -> B, blk1 = h + x_res
        bias_v(B1 + wcol, acc);
        accum_v<64, 64>(W1 + wcol, Ab, lane, acc);
        #pragma unroll
        for (int q = 0; q < 16; ++q) {
            const int f = (wcol + q) * 64 + lane;
            Bb[f] = ftanh(acc[q]) + Ab[f];
        }
        __syncthreads();

        // L2: B -> C
        bias_v(B2 + wcol, acc);
        accum_v<64, 64>(W2 + wcol, Bb, lane, acc);
        #pragma unroll
        for (int q = 0; q < 16; ++q) Cb[(wcol + q) * 64 + lane] = ftanh(acc[q]);
        __syncthreads();

        // L3: C -> A
        bias_v(B3 + wcol, acc);
        accum_v<64, 64>(W3 + wcol, Cb, lane, acc);
        #pragma unroll
        for (int q = 0; q < 16; ++q) Ab[(wcol + q) * 64 + lane] = ftanh(acc[q]);
        __syncthreads();

        // L4: A -> B (in-place residual: blk2 = h + blk1 already in B)
        bias_v(B4 + wcol, acc);
        accum_v<64, 64>(W4 + wcol, Ab, lane, acc);
        #pragma unroll
        for (int q = 0; q < 16; ++q) {
            const int f = (wcol + q) * 64 + lane;
            Bb[f] = ftanh(acc[q]) + Bb[f];
        }
        __syncthreads();

        // L5: B -> A (cols 0..63) and B -> C (cols 64..127); disjoint writes
        bias_v(B5 + wcol, acc);
        accum_v<64, 128>(W5 + wcol, Bb, lane, acc);
        #pragma unroll
        for (int q = 0; q < 16; ++q) Ab[(wcol + q) * 64 + lane] = ftanh(acc[q]);

        bias_v(B5 + 64 + wcol, acc);
        accum_v<64, 128>(W5 + 64 + wcol, Bb, lane, acc);
        #pragma unroll
        for (int q = 0; q < 16; ++q) Cb[(wcol + q) * 64 + lane] = ftanh(acc[q]);
        __syncthreads();

        // L6: (A|C) -> out, 4 chunks of 64 cols; 16-lane segment reduce + atomics
        const float sm = SMb[lane];
        const int ct = CTb[lane];
        #pragma unroll 1
        for (int c0 = 0; c0 < 256; c0 += 64) {
            float a6[16];
            bias_v(B6 + c0 + wcol, a6);
            accum_v<64, 256>(W6 + c0 + wcol, Ab, lane, a6);            // kk 0..63
            accum_v<64, 256>(W6 + 64 * 256 + c0 + wcol, Cb, lane, a6); // kk 64..127
            #pragma unroll
            for (int q = 0; q < 16; ++q) {
                float v = ftanh(a6[q]) * sm;
                v += __shfl_xor(v, 1);
                v += __shfl_xor(v, 2);
                v += __shfl_xor(v, 4);
                v += __shfl_xor(v, 8);
                if (((lane & 15) == 0) && ct >= 0)
                    atomicAdd(out + (size_t)ct * 256 + c0 + wcol + q, v);
            }
        }
    }
}

} // namespace

extern "C" void kernel_launch(void* const* d_in, const int* in_sizes, int n_in,
                              void* d_out, int out_size, void* d_ws, size_t ws_size,
                              hipStream_t stream) {
    (void)in_sizes; (void)n_in;

    const float* D  = (const float*)d_in[0];
    const float* Z  = (const float*)d_in[1];
    const float* W0 = (const float*)d_in[2];  const float* B0 = (const float*)d_in[3];
    const float* W1 = (const float*)d_in[4];  const float* B1 = (const float*)d_in[5];
    const float* W2 = (const float*)d_in[6];  const float* B2 = (const float*)d_in[7];
    const float* W3 = (const float*)d_in[8];  const float* B3 = (const float*)d_in[9];
    const float* W4 = (const float*)d_in[10]; const float* B4 = (const float*)d_in[11];
    const float* W5 = (const float*)d_in[12]; const float* B5 = (const float*)d_in[13];
    const float* W6 = (const float*)d_in[14]; const float* B6 = (const float*)d_in[15];
    float* out = (float*)d_out;

    int* ctr = (int*)d_ws;
    float* rowbuf = (float*)((char*)d_ws + 64);
    size_t avail = (ws_size > 64) ? (ws_size - 64) / (REC * sizeof(float)) : 0;
    int maxrows = (int)((avail < (size_t)MAXROWS_HARD) ? avail : (size_t)MAXROWS_HARD);

    hipMemsetAsync(d_ws, 0, 64, stream);
    hipMemsetAsync(d_out, 0, sizeof(float) * (size_t)out_size, stream);

    feat_kernel<<<256, 256, 0, stream>>>(D, Z, rowbuf, ctr, maxrows);
    mlp_kernel<<<K2_BLOCKS, 256, 0, stream>>>(rowbuf, ctr,
                                              W0, B0, W1, B1, W2, B2, W3, B3,
                                              W4, B4, W5, B5, W6, B6, out, maxrows);
}

// Round 9
// 388.932 us; speedup vs baseline: 2.0300x; 2.0300x over previous
//
#include <hip/hip_runtime.h>

namespace {

constexpr int T = 465;        // (N-1)(N-2)/2 triplets per center
constexpr float FCUT = 3.5f;
constexpr float PI_OVER_CUT = 0.8975979010256552f; // pi/3.5
constexpr int REC = 12;       // floats per compacted row record
constexpr int K2_BLOCKS = 512;
constexpr int MAXROWS_HARD = 1024 * 480;

__device__ __forceinline__ float ftanh(float x) {
    x = fminf(fmaxf(x, -15.0f), 15.0f);
    const float e = __expf(2.0f * x);
    return (e - 1.0f) * __builtin_amdgcn_rcpf(e + 1.0f);
}

// broadcast lane l of v to all lanes (SGPR path; no LDS, no shuffle network)
__device__ __forceinline__ float rl_f(float v, int l) {
    return __int_as_float(__builtin_amdgcn_readlane(__float_as_int(v), l));
}

// closed-form unrank of t in [0,465) -> pair (a,b), 0<=a<b<31 (M=31)
__device__ __forceinline__ void unrank(int t, int i, int& j, int& k) {
    int a = (int)((61.0f - sqrtf(3721.0f - 8.0f * (float)t)) * 0.5f);
    a = a < 0 ? 0 : (a > 29 ? 29 : a);
    int rem = t - ((a * (61 - a)) >> 1);
    while (rem < 0) { --a; rem = t - ((a * (61 - a)) >> 1); }
    while (rem >= 30 - a) { rem -= 30 - a; ++a; }
    const int b = a + 1 + rem;
    j = a + (a >= i);
    k = b + (b >= i);
}

// ---------------- K1: compact active triplets into global row list ----------
__global__ __launch_bounds__(256, 4)
void feat_kernel(const float* __restrict__ D, const float* __restrict__ Z,
                 float* __restrict__ rows, int* __restrict__ ctr, int maxrows)
{
    const int lane = threadIdx.x & 63;
    const int center = blockIdx.x * 4 + (threadIdx.x >> 6);
    const int bi = center >> 5, i = center & 31;
    const float* __restrict__ Drow = D + bi * 1024;
    const float* __restrict__ Zrow = Z + bi * 32;
    const float z_i = Zrow[i];

    unsigned long long masks[8];
    int cnt = 0;
    #pragma unroll
    for (int rnd = 0; rnd < 8; ++rnd) {
        const int t = rnd * 64 + lane;
        bool act = false;
        if (t < T) {
            int j, k;
            unrank(t, i, j, k);
            const float rij = Drow[i * 32 + j];
            const float rik = Drow[i * 32 + k];
            act = (rij < FCUT) && (rik < FCUT);
        }
        masks[rnd] = __ballot(act);
        cnt += (int)__popcll(masks[rnd]);
    }
    const int padded = (cnt + 15) & ~15;   // every 16-segment belongs to one center
    if (padded == 0) return;
    int base = 0;
    if (lane == 0) base = atomicAdd(ctr, padded);
    base = __shfl(base, 0);
    if (base + padded > maxrows) return;

    int pre = 0;
    #pragma unroll
    for (int rnd = 0; rnd < 8; ++rnd) {
        const unsigned long long mb = masks[rnd];
        const bool act = (mb >> lane) & 1ull;
        const int slot = base + pre + (int)__popcll(mb & ((1ull << lane) - 1ull));
        pre += (int)__popcll(mb);
        if (act) {
            const int t = rnd * 64 + lane;
            int j, k;
            unrank(t, i, j, k);
            const float rij = Drow[i * 32 + j];
            const float rik = Drow[i * 32 + k];
            const float rjk = Drow[j * 32 + k];
            const float zj = Zrow[j], zk = Zrow[k];
            const float rij2 = rij * rij, rik2 = rik * rik, rjk2 = rjk * rjk;
            const float ci = (rij2 + rik2 - rjk2) * __builtin_amdgcn_rcpf(fmaxf(2.f * rij * rik, 1e-10f));
            const float cj = (rij2 + rjk2 - rik2) * __builtin_amdgcn_rcpf(fmaxf(2.f * rij * rjk, 1e-10f));
            const float ck = (rik2 + rjk2 - rij2) * __builtin_amdgcn_rcpf(fmaxf(2.f * rik * rjk, 1e-10f));
            const float g0 = rij + rik + rjk;
            const float g1 = rij * rik + rij * rjk + rik * rjk;
            const float g2 = rij * rik * rjk;
            const float rg = __builtin_amdgcn_rcpf(sqrtf(g0 * g0 + g1 * g1 + g2 * g2) + 1e-7f);
            const float s0 = z_i + zj + zk;
            const float s1 = ci + cj + ck;
            const float s2 = z_i * (zj + zk) + zj * zk - ci * (cj + ck) - cj * ck;
            const float s3 = z_i * (cj + ck) + ci * (zj + zk) + zj * ck + cj * zk;
            const float s4 = z_i * (zj * zk - cj * ck) - ci * (zj * ck + cj * zk);
            const float s5 = z_i * (zj * ck + cj * zk) + ci * (zj * zk - cj * ck);
            const float rs = __builtin_amdgcn_rcpf(sqrtf(s0*s0 + s1*s1 + s2*s2 + s3*s3 + s4*s4 + s5*s5) + 1e-7f);
            const float fij = 0.5f * __cosf(PI_OVER_CUT * rij) + 0.5f;
            const float fik = 0.5f * __cosf(PI_OVER_CUT * rik) + 0.5f;
            float4* dst = (float4*)(rows + (size_t)slot * REC);
            dst[0] = make_float4(g0 * rg, g1 * rg, g2 * rg, s0 * rs);
            dst[1] = make_float4(s1 * rs, s2 * rs, s3 * rs, s4 * rs);
            dst[2] = make_float4(s5 * rs, fij * fik, __int_as_float(center), 0.f);
        }
    }
    for (int p = cnt + lane; p < padded; p += 64) {
        float4* dst = (float4*)(rows + (size_t)(base + p) * REC);
        dst[0] = make_float4(0.f, 0.f, 0.f, 0.f);
        dst[1] = make_float4(0.f, 0.f, 0.f, 0.f);
        dst[2] = make_float4(0.f, 0.f, __int_as_float(center), 0.f);
    }
}

// a[r] += sum_{k<64} readlane(x[r],k) * Wl[k*LDW]   (Wl pre-offset by lane+col)
// weights stream through 8 VGPRs per 8-k chunk; no LDS anywhere.
template<int LDW>
__device__ __forceinline__ void accum64(const float* __restrict__ Wl,
                                        const float (&x)[16], float (&a)[16])
{
    #pragma unroll 1
    for (int kc = 0; kc < 8; ++kc) {
        float w[8];
        #pragma unroll
        for (int k = 0; k < 8; ++k) w[k] = Wl[(size_t)(kc * 8 + k) * LDW];
        const int kb = kc * 8;
        #pragma unroll
        for (int r = 0; r < 16; ++r) {
            #pragma unroll
            for (int k = 0; k < 8; ++k)
                a[r] = fmaf(rl_f(x[r], kb + k), w[k], a[r]);
        }
    }
}

// paired variant: one readlane feeds two output column-slices (a1, a2)
template<int LDW>
__device__ __forceinline__ void accum64_pair(const float* __restrict__ Wl1,
                                             const float* __restrict__ Wl2,
                                             const float (&x)[16],
                                             float (&a1)[16], float (&a2)[16])
{
    #pragma unroll 1
    for (int kc = 0; kc < 8; ++kc) {
        float w1[8], w2[8];
        #pragma unroll
        for (int k = 0; k < 8; ++k) {
            w1[k] = Wl1[(size_t)(kc * 8 + k) * LDW];
            w2[k] = Wl2[(size_t)(kc * 8 + k) * LDW];
        }
        const int kb = kc * 8;
        #pragma unroll
        for (int r = 0; r < 16; ++r) {
            #pragma unroll
            for (int k = 0; k < 8; ++k) {
                const float s = rl_f(x[r], kb + k);
                a1[r] = fmaf(s, w1[k], a1[r]);
                a2[r] = fmaf(s, w2[k], a2[r]);
            }
        }
    }
}

// ---------------- K2: MLP, one 16-row segment (= one center) per wave -------
// Activations: 16 cross-lane vectors (reg x[r], lane = feature index).
// Weights: per-lane VGPRs (w[k], lane = output col), k-chunked.
// Inner loop: v_readlane broadcast + vector FMA. No LDS at all.
__global__ __launch_bounds__(256, 2)
void mlp_kernel(const float* __restrict__ rows, const int* __restrict__ ctr,
                const float* __restrict__ W0, const float* __restrict__ B0,
                const float* __restrict__ W1, const float* __restrict__ B1,
                const float* __restrict__ W2, const float* __restrict__ B2,
                const float* __restrict__ W3, const float* __restrict__ B3,
                const float* __restrict__ W4, const float* __restrict__ B4,
                const float* __restrict__ W5, const float* __restrict__ B5,
                const float* __restrict__ W6, const float* __restrict__ B6,
                float* __restrict__ out, int maxrows)
{
    const int lane = threadIdx.x & 63;
    const int gw = blockIdx.x * 4 + (threadIdx.x >> 6);   // global wave id
    constexpr int TOTW = K2_BLOCKS * 4;

    int nrows = *ctr;                 // multiple of 16
    if (nrows > maxrows) nrows = maxrows & ~15;
    const int nsegs = nrows >> 4;

    for (int s = gw; s < nsegs; s += TOTW) {
        // ---- load the 16-row segment: lane<12 holds record field `lane` ----
        float recv[16];
        const float* __restrict__ rp = rows + (size_t)s * 16 * REC;
        #pragma unroll
        for (int r = 0; r < 16; ++r)
            recv[r] = (lane < REC) ? rp[r * REC + lane] : 0.f;

        const int ct = __builtin_amdgcn_readlane(__float_as_int(recv[0]), 10);
        float smr[16];                 // uniform (SGPR) smooth weights
        #pragma unroll
        for (int r = 0; r < 16; ++r) smr[r] = rl_f(recv[r], 9);

        float x[16], res[16];

        // ---- L0: 9 -> 64 ----
        {
            float w0[9];
            #pragma unroll
            for (int k = 0; k < 9; ++k) w0[k] = W0[k * 64 + lane];
            const float b = B0[lane];
            #pragma unroll
            for (int r = 0; r < 16; ++r) {
                float a = b;
                #pragma unroll
                for (int k = 0; k < 9; ++k)
                    a = fmaf(rl_f(recv[r], k), w0[k], a);
                x[r] = ftanh(a);
            }
        }
        // ---- L1 ; blk1 = tanh + x_res ----
        {
            float a[16]; const float b = B1[lane];
            #pragma unroll
            for (int r = 0; r < 16; ++r) a[r] = b;
            accum64<64>(W1 + lane, x, a);
            #pragma unroll
            for (int r = 0; r < 16; ++r) { x[r] = ftanh(a[r]) + x[r]; res[r] = x[r]; }
        }
        // ---- L2 ----
        {
            float a[16]; const float b = B2[lane];
            #pragma unroll
            for (int r = 0; r < 16; ++r) a[r] = b;
            accum64<64>(W2 + lane, x, a);
            #pragma unroll
            for (int r = 0; r < 16; ++r) x[r] = ftanh(a[r]);
        }
        // ---- L3 ----
        {
            float a[16]; const float b = B3[lane];
            #pragma unroll
            for (int r = 0; r < 16; ++r) a[r] = b;
            accum64<64>(W3 + lane, x, a);
            #pragma unroll
            for (int r = 0; r < 16; ++r) x[r] = ftanh(a[r]);
        }
        // ---- L4 ; blk2 = tanh + blk1 ----
        {
            float a[16]; const float b = B4[lane];
            #pragma unroll
            for (int r = 0; r < 16; ++r) a[r] = b;
            accum64<64>(W4 + lane, x, a);
            #pragma unroll
            for (int r = 0; r < 16; ++r) x[r] = ftanh(a[r]) + res[r];
        }
        // ---- L5: 64 -> 128 (two 64-col halves) ----
        float xA[16], xB[16];
        {
            float a[16]; const float b = B5[lane];
            #pragma unroll
            for (int r = 0; r < 16; ++r) a[r] = b;
            accum64<128>(W5 + lane, x, a);
            #pragma unroll
            for (int r = 0; r < 16; ++r) xA[r] = ftanh(a[r]);
        }
        {
            float a[16]; const float b = B5[64 + lane];
            #pragma unroll
            for (int r = 0; r < 16; ++r) a[r] = b;
            accum64<128>(W5 + 64 + lane, x, a);
            #pragma unroll
            for (int r = 0; r < 16; ++r) xB[r] = ftanh(a[r]);
        }
        // ---- L6: 128 -> 256 ; paired col-slices; in-register row reduction ----
        #pragma unroll 1
        for (int p = 0; p < 2; ++p) {
            float a1[16], a2[16];
            const float b1 = B6[p * 128 + lane];
            const float b2 = B6[p * 128 + 64 + lane];
            #pragma unroll
            for (int r = 0; r < 16; ++r) { a1[r] = b1; a2[r] = b2; }
            accum64_pair<256>(W6 + p * 128 + lane,
                              W6 + p * 128 + 64 + lane, xA, a1, a2);
            accum64_pair<256>(W6 + 64 * 256 + p * 128 + lane,
                              W6 + 64 * 256 + p * 128 + 64 + lane, xB, a1, a2);
            float o1 = 0.f, o2 = 0.f;
            #pragma unroll
            for (int r = 0; r < 16; ++r) {
                o1 = fmaf(smr[r], ftanh(a1[r]), o1);
                o2 = fmaf(smr[r], ftanh(a2[r]), o2);
            }
            atomicAdd(out + (size_t)ct * 256 + p * 128 + lane, o1);
            atomicAdd(out + (size_t)ct * 256 + p * 128 + 64 + lane, o2);
        }
    }
}

} // namespace

extern "C" void kernel_launch(void* const* d_in, const int* in_sizes, int n_in,
                              void* d_out, int out_size, void* d_ws, size_t ws_size,
                              hipStream_t stream) {
    (void)in_sizes; (void)n_in;

    const float* D  = (const float*)d_in[0];
    const float* Z  = (const float*)d_in[1];
    const float* W0 = (const float*)d_in[2];  const float* B0 = (const float*)d_in[3];
    const float* W1 = (const float*)d_in[4];  const float* B1 = (const float*)d_in[5];
    const float* W2 = (const float*)d_in[6];  const float* B2 = (const float*)d_in[7];
    const float* W3 = (const float*)d_in[8];  const float* B3 = (const float*)d_in[9];
    const float* W4 = (const float*)d_in[10]; const float* B4 = (const float*)d_in[11];
    const float* W5 = (const float*)d_in[12]; const float* B5 = (const float*)d_in[13];
    const float* W6 = (const float*)d_in[14]; const float* B6 = (const float*)d_in[15];
    float* out = (float*)d_out;

    int* ctr = (int*)d_ws;
    float* rowbuf = (float*)((char*)d_ws + 64);
    size_t avail = (ws_size > 64) ? (ws_size - 64) / (REC * sizeof(float)) : 0;
    int maxrows = (int)((avail < (size_t)MAXROWS_HARD) ? avail : (size_t)MAXROWS_HARD);

    hipMemsetAsync(d_ws, 0, 64, stream);
    hipMemsetAsync(d_out, 0, sizeof(float) * (size_t)out_size, stream);

    feat_kernel<<<256, 256, 0, stream>>>(D, Z, rowbuf, ctr, maxrows);
    mlp_kernel<<<K2_BLOCKS, 256, 0, stream>>>(rowbuf, ctr,
                                              W0, B0, W1, B1, W2, B2, W3, B3,
                                              W4, B4, W5, B5, W6, B6, out, maxrows);
}